// Round 9
// baseline (262.074 us; speedup 1.0000x reference)
//
#include <hip/hip_runtime.h>
#include <cstddef>
#include <cstring>

#define NN 50000
#define NNP 50048
#define NE 800000
#define D 128
#define NG 512
#define BN_EPS 1e-5f
#define RSZC 25000    // count: nodes per range (2 ranges, 100 KB dyn LDS)
#define RSZF 12500    // fill: nodes per range (4 ranges, 50 KB LDS)
#define NCHUNK 64
#define CSZ 12500     // edges per chunk

typedef __bf16 bf16_t;
typedef __bf16 bf16x8 __attribute__((ext_vector_type(8)));
typedef float f32x4 __attribute__((ext_vector_type(4)));

// ---- workspace layout (float offsets) ----
#define OFF_ACCN 0            // float[4*512]
#define OFF_ACCE 2048         // float[4*512]
#define ZERO_FLOATS 4096      // only the accumulators need zeroing
#define OFF_DIS  4096         // float[50048]
#define OFF_CNT  54144        // int[50048]
#define OFF_COLP 104192       // int[50048]
#define OFF_ENDS 154240       // int[50048]
#define OFF_BSUM 204288       // int[256]
#define OFF_T1   204800       // float[50048]
#define OFF_T2   254848       // float[50048]
#define OFF_BP   304896       // float[3*128 padded]
#define OFF_WPT  305408       // bf16[3*128*128] (24576 floats)
#define OFF_PR   329984       // int[64][50048] = 3203072
#define OFF_PC   3533056      // int[64][50048] = 3203072 (CPS after csr_mid)
#define OFF_SRCS2 OFF_PR      // int2[800000], aliases PR (dead after csr_mid)
#define OFF_HBFA 7536128      // bf16[50048*128] (3203072 floats)
#define OFF_HBFB 10739200     // bf16[50048*128]

// ---- output layout (float offsets in d_out) ----
#define O_NKEY 0
#define O_EKEY 50000
#define O_NKN  850000
#define O_NEN  850512
#define O_EKN  851024
#define O_EEN  851536
#define O_NZN  852048
#define O_NZE  852560

__device__ __forceinline__ float sigmoidf(float x) {
    return 1.0f / (1.0f + expf(-x));
}

__device__ __forceinline__ unsigned short f2bf_bits(float f) {
    bf16_t h = (bf16_t)f;
    unsigned short u;
    __builtin_memcpy(&u, &h, 2);
    return u;
}

__device__ __forceinline__ float bf_lo(unsigned int u) {
    return __uint_as_float(u << 16);
}
__device__ __forceinline__ float bf_hi(unsigned int u) {
    return __uint_as_float(u & 0xFFFF0000u);
}

// Fold BN into weights, transpose, cast bf16
__global__ void prep_w(const float* __restrict__ W, const float* __restrict__ gamma,
                       const float* __restrict__ beta, const float* __restrict__ mean,
                       const float* __restrict__ var, bf16_t* __restrict__ Wpt,
                       float* __restrict__ bp) {
    int l = blockIdx.x;
    int j = threadIdx.x;
    float acc = 0.f;
    for (int k = 0; k < D; ++k) {
        float a = gamma[l * D + k] * rsqrtf(var[l * D + k] + BN_EPS);
        float c = beta[l * D + k] - mean[l * D + k] * a;
        float w = W[l * D * D + k * D + j];
        Wpt[l * D * D + j * D + k] = (bf16_t)(a * w);
        acc = fmaf(c, w, acc);
    }
    bp[l * D + j] = acc;
}

// partitioned LDS histogram (no global atomics); 2 node ranges of 25000 (R7 proven)
__global__ __launch_bounds__(256) void count_part(const int* __restrict__ ei,
                                                  int* __restrict__ PR,
                                                  int* __restrict__ PC) {
    extern __shared__ int hist[];
    const int r = blockIdx.x, p = blockIdx.y, dirz = blockIdx.z;
    const int tid = threadIdx.x;
    for (int i = tid; i < RSZC; i += 256) hist[i] = 0;
    __syncthreads();
    const int base = r * RSZC;
    const int4* ids = (const int4*)(ei + dirz * NE + p * CSZ);
    for (int i = tid; i < CSZ / 4; i += 256) {
        int4 v = ids[i];
        int d0 = v.x - base, d1 = v.y - base, d2 = v.z - base, d3 = v.w - base;
        if ((unsigned)d0 < RSZC) atomicAdd(&hist[d0], 1);
        if ((unsigned)d1 < RSZC) atomicAdd(&hist[d1], 1);
        if ((unsigned)d2 < RSZC) atomicAdd(&hist[d2], 1);
        if ((unsigned)d3 < RSZC) atomicAdd(&hist[d3], 1);
    }
    __syncthreads();
    int* dst = (dirz == 0 ? PR : PC) + p * NNP + base;
    for (int i = tid; i < RSZC; i += 256) dst[i] = hist[i];
}

// fused: rowsum->dis, colscan->cnt + per-chunk offsets in PC, block-local scan1
__global__ void csr_mid(const int* __restrict__ PR, int* __restrict__ PC,
                        float* __restrict__ dis, int* __restrict__ cnt,
                        int* __restrict__ colp, int* __restrict__ bsum) {
    __shared__ int s[256];
    int t = threadIdx.x;
    int i = blockIdx.x * 256 + t;
    int run = 0;
    if (i < NN) {
        int dg = 0;
#pragma unroll 8
        for (int k = 0; k < NCHUNK; ++k) dg += PR[k * NNP + i];
        dis[i] = rsqrtf((float)(dg + 1));
        for (int k = 0; k < NCHUNK; ++k) {
            int v = PC[k * NNP + i];
            PC[k * NNP + i] = run;
            run += v;
        }
        cnt[i] = run;
    }
    s[t] = run;
    __syncthreads();
    for (int o = 1; o < 256; o <<= 1) {
        int add = (t >= o) ? s[t - o] : 0;
        __syncthreads();
        s[t] += add;
        __syncthreads();
    }
    if (i < NN) colp[i] = s[t] - run;  // local exclusive
    if (t == 255) bsum[blockIdx.x] = s[255];
}

// scan3 with inlined block-offset reduction (absorbs old scan2)
__global__ void scan3(int* __restrict__ colp, const int* __restrict__ bsum,
                      const int* __restrict__ cnt, int* __restrict__ ends) {
    __shared__ int s[256];
    int t = threadIdx.x;
    int bid = blockIdx.x;
    s[t] = (t < bid) ? bsum[t] : 0;   // NB=196 <= 256
    __syncthreads();
    for (int o = 128; o; o >>= 1) {
        if (t < o) s[t] += s[t + o];
        __syncthreads();
    }
    int boff = s[0];
    int i = bid * 256 + t;
    if (i < NN) {
        int v = colp[i] + boff;
        colp[i] = v;
        ends[i] = v + cnt[i];
    }
}

// atomic-free(global) CSR fill; writes (src, dis[src]) pairs
__global__ __launch_bounds__(256) void fill_part(const int* __restrict__ ei,
                                                 const int* __restrict__ colp,
                                                 const int* __restrict__ CPS,
                                                 const float* __restrict__ dis,
                                                 int2* __restrict__ srcs2) {
    __shared__ int curs[RSZF];
    const int r = blockIdx.x, p = blockIdx.y;
    const int tid = threadIdx.x;
    const int base = r * RSZF;
    for (int i = tid; i < RSZF; i += 256)
        curs[i] = colp[base + i] + CPS[p * NNP + base + i];
    __syncthreads();
    const int4* rows = (const int4*)(ei + p * CSZ);
    const int4* cols = (const int4*)(ei + NE + p * CSZ);
    for (int i = tid; i < CSZ / 4; i += 256) {
        int4 rv = rows[i];
        int4 cv = cols[i];
        int d;
        d = cv.x - base;
        if ((unsigned)d < RSZF)
            srcs2[atomicAdd(&curs[d], 1)] = make_int2(rv.x, __float_as_int(dis[rv.x]));
        d = cv.y - base;
        if ((unsigned)d < RSZF)
            srcs2[atomicAdd(&curs[d], 1)] = make_int2(rv.y, __float_as_int(dis[rv.y]));
        d = cv.z - base;
        if ((unsigned)d < RSZF)
            srcs2[atomicAdd(&curs[d], 1)] = make_int2(rv.z, __float_as_int(dis[rv.z]));
        d = cv.w - base;
        if ((unsigned)d < RSZF)
            srcs2[atomicAdd(&curs[d], 1)] = make_int2(rv.w, __float_as_int(dis[rv.w]));
    }
}

// MFMA bf16 GEMM: out[NNx128] = act(A[NNx128] @ B + bias). Bt is col-major bf16.
template <int AMODE, bool ORELU>
__global__ __launch_bounds__(256) void gemm_mfma(const void* __restrict__ Aptr,
                                                 const bf16_t* __restrict__ Bt,
                                                 const float* __restrict__ bias,
                                                 bf16_t* __restrict__ out) {
    const int tid = threadIdx.x;
    const int wv = tid >> 6;
    const int lane = tid & 63;
    const int l15 = lane & 15;
    const int l4 = lane >> 4;
    const int row0 = blockIdx.x * 64 + wv * 16;

    bf16x8 afrag[4];
    {
        int r = row0 + l15;
        int rc = (r < NN) ? r : (NN - 1);
#pragma unroll
        for (int kk = 0; kk < 4; ++kk) {
            int off = rc * D + kk * 32 + l4 * 8;
            if (AMODE == 0) {
                const float* A = (const float*)Aptr;
                float4 f0 = *(const float4*)(A + off);
                float4 f1 = *(const float4*)(A + off + 4);
                bf16x8 a;
                a[0] = (bf16_t)f0.x; a[1] = (bf16_t)f0.y;
                a[2] = (bf16_t)f0.z; a[3] = (bf16_t)f0.w;
                a[4] = (bf16_t)f1.x; a[5] = (bf16_t)f1.y;
                a[6] = (bf16_t)f1.z; a[7] = (bf16_t)f1.w;
                afrag[kk] = a;
            } else {
                const bf16_t* A = (const bf16_t*)Aptr;
                afrag[kk] = *(const bf16x8*)(A + off);
            }
        }
    }

    f32x4 acc[8];
#pragma unroll
    for (int n = 0; n < 8; ++n) acc[n] = (f32x4){0.f, 0.f, 0.f, 0.f};

#pragma unroll
    for (int n = 0; n < 8; ++n) {
#pragma unroll
        for (int kk = 0; kk < 4; ++kk) {
            bf16x8 bfrag = *(const bf16x8*)(Bt + (n * 16 + l15) * D + kk * 32 + l4 * 8);
            acc[n] = __builtin_amdgcn_mfma_f32_16x16x32_bf16(afrag[kk], bfrag, acc[n], 0, 0, 0);
        }
    }

#pragma unroll
    for (int n = 0; n < 8; ++n) {
        int col = n * 16 + l15;
        float bv = bias[col];
#pragma unroll
        for (int r = 0; r < 4; ++r) {
            int row = row0 + l4 * 4 + r;
            if (row < NN) {
                float v = acc[n][r] + bv;
                if (ORELU) v = fmaxf(v, 0.f);
                out[(size_t)row * D + col] = (bf16_t)v;
            }
        }
    }
}

// FUSED prop1 + GEMM2: gather 64 rows of relu(P(hin)+bh0) into LDS (swizzled),
// then MFMA from LDS: out = LDSrows @ Wpt2 + bp2. Kills the 25.6 MB round trip.
__global__ __launch_bounds__(256) void prop_gemm(
    const int* __restrict__ colp, const int* __restrict__ ends,
    const int2* __restrict__ srcs2, const float* __restrict__ dis,
    const bf16_t* __restrict__ hin, const float* __restrict__ bias_pre,
    const bf16_t* __restrict__ Bt, const float* __restrict__ bias_post,
    bf16_t* __restrict__ out) {
    __shared__ __align__(16) unsigned short As[64 * 128];  // bf16 bits, XOR-swizzled
    const int tid = threadIdx.x;
    const int wv = tid >> 6;
    const int lane = tid & 63;
    const int row0 = blockIdx.x * 64;
    float2 bb = ((const float2*)bias_pre)[lane];

    // ---- gather phase: wave wv produces rows wv*16 .. wv*16+15 ----
    for (int it = 0; it < 16; ++it) {
        const int rl = wv * 16 + it;
        const int n = __builtin_amdgcn_readfirstlane(row0 + rl);
        unsigned int pk = 0;
        if (n < NN) {
            const int start = colp[n];
            const int end = ends[n];
            const float dn = dis[n];
            unsigned int u = ((const unsigned int*)(hin + (size_t)n * D))[lane];
            float ax = dn * bf_lo(u), ay = dn * bf_hi(u);
            int i = start;
            for (; i + 3 < end; i += 4) {
                int2 e0 = srcs2[i], e1 = srcs2[i + 1], e2 = srcs2[i + 2], e3 = srcs2[i + 3];
                unsigned int u0 = ((const unsigned int*)(hin + (size_t)e0.x * D))[lane];
                unsigned int u1 = ((const unsigned int*)(hin + (size_t)e1.x * D))[lane];
                unsigned int u2 = ((const unsigned int*)(hin + (size_t)e2.x * D))[lane];
                unsigned int u3 = ((const unsigned int*)(hin + (size_t)e3.x * D))[lane];
                float w0 = __int_as_float(e0.y), w1 = __int_as_float(e1.y);
                float w2 = __int_as_float(e2.y), w3 = __int_as_float(e3.y);
                ax = fmaf(w0, bf_lo(u0), ax); ay = fmaf(w0, bf_hi(u0), ay);
                ax = fmaf(w1, bf_lo(u1), ax); ay = fmaf(w1, bf_hi(u1), ay);
                ax = fmaf(w2, bf_lo(u2), ax); ay = fmaf(w2, bf_hi(u2), ay);
                ax = fmaf(w3, bf_lo(u3), ax); ay = fmaf(w3, bf_hi(u3), ay);
            }
            for (; i < end; ++i) {
                int2 e0 = srcs2[i];
                unsigned int u0 = ((const unsigned int*)(hin + (size_t)e0.x * D))[lane];
                float w0 = __int_as_float(e0.y);
                ax = fmaf(w0, bf_lo(u0), ax); ay = fmaf(w0, bf_hi(u0), ay);
            }
            float vx = fmaxf(dn * ax + bb.x, 0.f);
            float vy = fmaxf(dn * ay + bb.y, 0.f);
            pk = (unsigned int)f2bf_bits(vx) | ((unsigned int)f2bf_bits(vy) << 16);
        }
        // swizzled store: 16B unit c = lane>>2, stored at c ^ (rl&7)
        int cs = (lane >> 2) ^ (rl & 7);
        *((unsigned int*)&As[rl * 128 + cs * 8] + (lane & 3)) = pk;
    }
    __syncthreads();

    // ---- GEMM phase: A-fragments from LDS ----
    const int l15 = lane & 15;
    const int l4 = lane >> 4;
    const int rl = wv * 16 + l15;
    bf16x8 afrag[4];
#pragma unroll
    for (int kk = 0; kk < 4; ++kk) {
        int cs = (kk * 4 + l4) ^ (rl & 7);
        afrag[kk] = *(const bf16x8*)&As[rl * 128 + cs * 8];
    }

    f32x4 acc[8];
#pragma unroll
    for (int n = 0; n < 8; ++n) acc[n] = (f32x4){0.f, 0.f, 0.f, 0.f};
#pragma unroll
    for (int n = 0; n < 8; ++n) {
#pragma unroll
        for (int kk = 0; kk < 4; ++kk) {
            bf16x8 bfrag = *(const bf16x8*)(Bt + (n * 16 + l15) * D + kk * 32 + l4 * 8);
            acc[n] = __builtin_amdgcn_mfma_f32_16x16x32_bf16(afrag[kk], bfrag, acc[n], 0, 0, 0);
        }
    }
#pragma unroll
    for (int n = 0; n < 8; ++n) {
        int col = n * 16 + l15;
        float bv = bias_post[col];
#pragma unroll
        for (int r = 0; r < 4; ++r) {
            int row = row0 + wv * 16 + l4 * 4 + r;
            if (row < NN) out[(size_t)row * D + col] = (bf16_t)(acc[n][r] + bv);
        }
    }
}

// standalone gather propagate (prop2): one wave per node, unroll x4 (R7 proven)
__global__ __launch_bounds__(256) void prop_gather(
    const int* __restrict__ colp, const int* __restrict__ ends,
    const int2* __restrict__ srcs2, const float* __restrict__ dis,
    const bf16_t* __restrict__ hin, bf16_t* __restrict__ hout) {
    int n = blockIdx.x * 4 + (threadIdx.x >> 6);
    n = __builtin_amdgcn_readfirstlane(n);
    int lane = threadIdx.x & 63;
    if (n >= NN) return;
    const int start = colp[n];
    const int end = ends[n];
    const float dn = dis[n];
    unsigned int u = ((const unsigned int*)(hin + (size_t)n * D))[lane];
    float ax = dn * bf_lo(u), ay = dn * bf_hi(u);
    int i = start;
    for (; i + 3 < end; i += 4) {
        int2 e0 = srcs2[i], e1 = srcs2[i + 1], e2 = srcs2[i + 2], e3 = srcs2[i + 3];
        unsigned int u0 = ((const unsigned int*)(hin + (size_t)e0.x * D))[lane];
        unsigned int u1 = ((const unsigned int*)(hin + (size_t)e1.x * D))[lane];
        unsigned int u2 = ((const unsigned int*)(hin + (size_t)e2.x * D))[lane];
        unsigned int u3 = ((const unsigned int*)(hin + (size_t)e3.x * D))[lane];
        float w0 = __int_as_float(e0.y), w1 = __int_as_float(e1.y);
        float w2 = __int_as_float(e2.y), w3 = __int_as_float(e3.y);
        ax = fmaf(w0, bf_lo(u0), ax); ay = fmaf(w0, bf_hi(u0), ay);
        ax = fmaf(w1, bf_lo(u1), ax); ay = fmaf(w1, bf_hi(u1), ay);
        ax = fmaf(w2, bf_lo(u2), ax); ay = fmaf(w2, bf_hi(u2), ay);
        ax = fmaf(w3, bf_lo(u3), ax); ay = fmaf(w3, bf_hi(u3), ay);
    }
    for (; i < end; ++i) {
        int2 e0 = srcs2[i];
        unsigned int u0 = ((const unsigned int*)(hin + (size_t)e0.x * D))[lane];
        float w0 = __int_as_float(e0.y);
        ax = fmaf(w0, bf_lo(u0), ax); ay = fmaf(w0, bf_hi(u0), ay);
    }
    unsigned int pk = (unsigned int)f2bf_bits(dn * ax) | ((unsigned int)f2bf_bits(dn * ay) << 16);
    ((unsigned int*)(hout + (size_t)n * D))[lane] = pk;
}

// node head on bf16 node_rep: 32-lane groups, 4 bf16/lane
__global__ __launch_bounds__(256) void node_kernel(
    const bf16_t* __restrict__ h, const float* __restrict__ bh1,
    const float* __restrict__ We, const float* __restrict__ Wn,
    const float* __restrict__ bnb, const int* __restrict__ batch,
    float* __restrict__ nkey_out, float* __restrict__ t1, float* __restrict__ t2,
    float* __restrict__ accN) {
    __shared__ float binK[NG], binE[NG], binZ[NG], binC[NG];
    const int tid = threadIdx.x;
    for (int i = tid; i < NG; i += 256) { binK[i] = 0.f; binE[i] = 0.f; binZ[i] = 0.f; binC[i] = 0.f; }
    __syncthreads();

    const int CHUNK = 98;
    int start = blockIdx.x * CHUNK;
    int end = min(start + CHUNK, NN);
    int sub = tid >> 5;
    int l32 = tid & 31;
    float bnb0 = bnb[0];

    float4 w1 = ((const float4*)We)[l32];
    float4 w2 = ((const float4*)(We + D))[l32];
    float4 wn = ((const float4*)Wn)[l32];
    float4 bb = ((const float4*)bh1)[l32];

    for (int n = start + sub; n < end; n += 8) {
        uint2 pk = ((const uint2*)(h + (size_t)n * D))[l32];
        float v0 = bf_lo(pk.x) + bb.x;
        float v1 = bf_hi(pk.x) + bb.y;
        float v2 = bf_lo(pk.y) + bb.z;
        float v3 = bf_hi(pk.y) + bb.w;
        float s1 = v0 * w1.x + v1 * w1.y + v2 * w1.z + v3 * w1.w;
        float s2 = v0 * w2.x + v1 * w2.y + v2 * w2.z + v3 * w2.w;
        float s3 = v0 * wn.x + v1 * wn.y + v2 * wn.z + v3 * wn.w;
        for (int o = 16; o; o >>= 1) {
            s1 += __shfl_xor(s1, o);
            s2 += __shfl_xor(s2, o);
            s3 += __shfl_xor(s3, o);
        }
        if (l32 == 0) {
            t1[n] = s1;
            t2[n] = s2;
            float nk = sigmoidf(s3 + bnb0);
            nkey_out[n] = nk;
            int g = batch[n];
            atomicAdd(&binK[g], nk);
            atomicAdd(&binE[g], 1.0f - nk);
            if (nk > 0.f) atomicAdd(&binZ[g], 1.0f);
            atomicAdd(&binC[g], 1.0f);
        }
    }
    __syncthreads();
    if (start < NN) {
        int glo = batch[start];
        int ghi = batch[end - 1];
        for (int g = glo + tid; g <= ghi; g += 256) {
            unsafeAtomicAdd(&accN[g], binK[g]);
            unsafeAtomicAdd(&accN[NG + g], binE[g]);
            unsafeAtomicAdd(&accN[2 * NG + g], binZ[g]);
            unsafeAtomicAdd(&accN[3 * NG + g], binC[g]);
        }
    }
}

// edge head: 4 edges per thread via int4
__global__ __launch_bounds__(256) void edge_kernel(
    const int* __restrict__ ei, const float* __restrict__ t1,
    const float* __restrict__ t2, const float* __restrict__ be,
    const int* __restrict__ batch, float* __restrict__ ekey_out,
    float* __restrict__ accE) {
    __shared__ float binK[NG], binE[NG], binZ[NG], binC[NG];
    const int tid = threadIdx.x;
    for (int i = tid; i < NG; i += 256) { binK[i] = 0.f; binE[i] = 0.f; binZ[i] = 0.f; binC[i] = 0.f; }
    __syncthreads();
    float be0 = be[0];
    int stride4 = gridDim.x * 256;
    for (int q = blockIdx.x * 256 + tid; q < NE / 4; q += stride4) {
        int4 r4 = ((const int4*)ei)[q];
        int4 c4 = ((const int4*)(ei + NE))[q];
        float a0 = t1[r4.x], a1 = t1[r4.y], a2 = t1[r4.z], a3 = t1[r4.w];
        float b0 = t2[c4.x], b1 = t2[c4.y], b2 = t2[c4.z], b3 = t2[c4.w];
        int g0 = batch[r4.x], g1 = batch[r4.y], g2 = batch[r4.z], g3 = batch[r4.w];
        float e0 = sigmoidf(a0 + b0 + be0);
        float e1 = sigmoidf(a1 + b1 + be0);
        float e2 = sigmoidf(a2 + b2 + be0);
        float e3 = sigmoidf(a3 + b3 + be0);
        ((float4*)ekey_out)[q] = make_float4(e0, e1, e2, e3);
        atomicAdd(&binK[g0], e0); atomicAdd(&binE[g0], 1.0f - e0);
        if (e0 > 0.f) atomicAdd(&binZ[g0], 1.0f);
        atomicAdd(&binC[g0], 1.0f);
        atomicAdd(&binK[g1], e1); atomicAdd(&binE[g1], 1.0f - e1);
        if (e1 > 0.f) atomicAdd(&binZ[g1], 1.0f);
        atomicAdd(&binC[g1], 1.0f);
        atomicAdd(&binK[g2], e2); atomicAdd(&binE[g2], 1.0f - e2);
        if (e2 > 0.f) atomicAdd(&binZ[g2], 1.0f);
        atomicAdd(&binC[g2], 1.0f);
        atomicAdd(&binK[g3], e3); atomicAdd(&binE[g3], 1.0f - e3);
        if (e3 > 0.f) atomicAdd(&binZ[g3], 1.0f);
        atomicAdd(&binC[g3], 1.0f);
    }
    __syncthreads();
    for (int g = tid; g < NG; g += 256) {
        if (binC[g] != 0.f) {
            unsafeAtomicAdd(&accE[g], binK[g]);
            unsafeAtomicAdd(&accE[NG + g], binE[g]);
            unsafeAtomicAdd(&accE[2 * NG + g], binZ[g]);
            unsafeAtomicAdd(&accE[3 * NG + g], binC[g]);
        }
    }
}

__global__ void final_kernel(const float* __restrict__ accN,
                             const float* __restrict__ accE,
                             float* __restrict__ out) {
    int g = blockIdx.x * 256 + threadIdx.x;
    if (g < NG) {
        out[O_NKN + g] = accN[g] + 1e-8f;
        out[O_NEN + g] = accN[NG + g] + 1e-8f;
        out[O_EKN + g] = accE[g] + 1e-8f;
        out[O_EEN + g] = accE[NG + g] + 1e-8f;
        out[O_NZN + g] = accN[2 * NG + g] / accN[3 * NG + g];
        out[O_NZE + g] = accE[2 * NG + g] / accE[3 * NG + g];
    }
}

extern "C" void kernel_launch(void* const* d_in, const int* in_sizes, int n_in,
                              void* d_out, int out_size, void* d_ws, size_t ws_size,
                              hipStream_t stream) {
    const float* x     = (const float*)d_in[0];
    const int*   ei    = (const int*)d_in[1];
    const int*   batch = (const int*)d_in[2];
    const float* W     = (const float*)d_in[4];
    const float* bh    = (const float*)d_in[5];   // [2][128]
    const float* gamma = (const float*)d_in[6];
    const float* beta  = (const float*)d_in[7];
    const float* mean  = (const float*)d_in[8];
    const float* var   = (const float*)d_in[9];
    const float* We    = (const float*)d_in[10];
    const float* be    = (const float*)d_in[11];
    const float* Wn    = (const float*)d_in[12];
    const float* bnb   = (const float*)d_in[13];

    float* ws  = (float*)d_ws;
    float* out = (float*)d_out;

    float*  accN  = ws + OFF_ACCN;
    float*  accE  = ws + OFF_ACCE;
    float*  dis   = ws + OFF_DIS;
    int*    cnt   = (int*)(ws + OFF_CNT);
    int*    colp  = (int*)(ws + OFF_COLP);
    int*    ends  = (int*)(ws + OFF_ENDS);
    int*    bsum  = (int*)(ws + OFF_BSUM);
    float*  t1    = ws + OFF_T1;
    float*  t2    = ws + OFF_T2;
    float*  bp    = ws + OFF_BP;
    bf16_t* Wpt   = (bf16_t*)(ws + OFF_WPT);
    int*    PR    = (int*)(ws + OFF_PR);
    int*    PC    = (int*)(ws + OFF_PC);
    int2*   srcs2 = (int2*)(ws + OFF_SRCS2);   // aliases PR (dead after csr_mid)
    bf16_t* hbfA  = (bf16_t*)(ws + OFF_HBFA);
    bf16_t* hbfB  = (bf16_t*)(ws + OFF_HBFB);

    hipMemsetAsync(d_ws, 0, (size_t)ZERO_FLOATS * sizeof(float), stream);

    prep_w<<<3, 128, 0, stream>>>(W, gamma, beta, mean, var, Wpt, bp);

    // ---- atomic-free CSR build ----
    count_part<<<dim3(2, NCHUNK, 2), 256, RSZC * sizeof(int), stream>>>(ei, PR, PC);
    const int NB = (NN + 255) / 256;  // 196
    csr_mid<<<NB, 256, 0, stream>>>(PR, PC, dis, cnt, colp, bsum);
    scan3<<<NB, 256, 0, stream>>>(colp, bsum, cnt, ends);
    fill_part<<<dim3(4, NCHUNK), 256, 0, stream>>>(ei, colp, PC, dis, srcs2);

    const int GB = (NN + 63) / 64;  // 782
    // layer 0: hbfA = bf16(relu(x @ Wp0 + bp0))
    gemm_mfma<0, true><<<GB, 256, 0, stream>>>(x, Wpt, bp, hbfA);
    // layer 1 linear: hbfB = bf16(hbfA @ Wp1 + bp1)
    gemm_mfma<1, false><<<GB, 256, 0, stream>>>(hbfA, Wpt + D * D, bp + D, hbfB);
    // FUSED: hbfA = bf16( relu(P(hbfB)+bh0) @ Wp2 + bp2 )
    prop_gemm<<<GB, 256, 0, stream>>>(colp, ends, srcs2, dis, hbfB, bh,
                                      Wpt + 2 * D * D, bp + 2 * D, hbfA);
    // propagate 2: hbfB = bf16(P(hbfA))  (node_rep, bf16)
    prop_gather<<<12500, 256, 0, stream>>>(colp, ends, srcs2, dis, hbfA, hbfB);

    node_kernel<<<512, 256, 0, stream>>>(hbfB, bh + D, We, Wn, bnb, batch,
                                         out + O_NKEY, t1, t2, accN);
    edge_kernel<<<256, 256, 0, stream>>>(ei, t1, t2, be, batch, out + O_EKEY, accE);
    final_kernel<<<2, 256, 0, stream>>>(accN, accE, out);
}

// Round 10
// 246.584 us; speedup vs baseline: 1.0628x; 1.0628x over previous
//
#include <hip/hip_runtime.h>
#include <cstddef>
#include <cstring>

#define NN 50000
#define NNP 50048
#define NE 800000
#define D 128
#define NG 512
#define BN_EPS 1e-5f
#define RSZC 25000    // count: nodes per range (2 ranges, 100 KB dyn LDS)
#define RSZF 12500    // fill: nodes per range (4 ranges, 50 KB LDS)
#define NCHUNK 64
#define CSZ 12500     // edges per chunk
#define EDGE_BLOCKS 256

typedef __bf16 bf16_t;
typedef __bf16 bf16x8 __attribute__((ext_vector_type(8)));
typedef float f32x4 __attribute__((ext_vector_type(4)));

// ---- workspace layout (float offsets) ----
#define OFF_ACCN 0            // float[4*512]
#define OFF_ACCE 2048         // float[4*512]
#define OFF_CTR  4096         // int[1] + pad
#define ZERO_FLOATS 4160      // zeroed region = [0, here)
#define OFF_DIS  4160         // float[50048]
#define OFF_CNT  54208        // int[50048]
#define OFF_COLP 104256       // int[50048]
#define OFF_ENDS 154304       // int[50048]
#define OFF_BSUM 204352       // int[256]
#define OFF_T1   204800       // float[50048]
#define OFF_T2   254848       // float[50048]
#define OFF_BP   304896       // float[3*128 padded]
#define OFF_WPT  305408       // bf16[3*128*128] (24576 floats)
#define OFF_PR   329984       // int[64][50048] = 3203072
#define OFF_PC   3533056      // int[64][50048] = 3203072 (CPS after csr_mid)
#define OFF_SRCS OFF_PR       // uint[800000], aliases PR (dead after csr_mid)
#define OFF_HBFA 7536128      // bf16[50048*128] (3203072 floats)
#define OFF_HBFB 10739200     // bf16[50048*128]

// ---- output layout (float offsets in d_out) ----
#define O_NKEY 0
#define O_EKEY 50000
#define O_NKN  850000
#define O_NEN  850512
#define O_EKN  851024
#define O_EEN  851536
#define O_NZN  852048
#define O_NZE  852560

__device__ __forceinline__ float sigmoidf(float x) {
    return 1.0f / (1.0f + expf(-x));
}

__device__ __forceinline__ unsigned short f2bf_bits(float f) {
    bf16_t h = (bf16_t)f;
    unsigned short u;
    __builtin_memcpy(&u, &h, 2);
    return u;
}

__device__ __forceinline__ float bf_lo(unsigned int u) {
    return __uint_as_float(u << 16);
}
__device__ __forceinline__ float bf_hi(unsigned int u) {
    return __uint_as_float(u & 0xFFFF0000u);
}

// count histograms (2 node ranges x 64 chunks x 2 dirs) + prep_w rides on z==2.
__global__ __launch_bounds__(256) void count_prep(const int* __restrict__ ei,
                                                  int* __restrict__ PR,
                                                  int* __restrict__ PC,
                                                  const float* __restrict__ W,
                                                  const float* __restrict__ gamma,
                                                  const float* __restrict__ beta,
                                                  const float* __restrict__ mean,
                                                  const float* __restrict__ var,
                                                  bf16_t* __restrict__ Wpt,
                                                  float* __restrict__ bp) {
    const int tid = threadIdx.x;
    if (blockIdx.z == 2) {
        // prep_w: fold BN into weights, transpose, cast bf16
        if (blockIdx.x == 0 && blockIdx.y < 3 && tid < D) {
            int l = blockIdx.y;
            int j = tid;
            float acc = 0.f;
            for (int k = 0; k < D; ++k) {
                float a = gamma[l * D + k] * rsqrtf(var[l * D + k] + BN_EPS);
                float c = beta[l * D + k] - mean[l * D + k] * a;
                float w = W[l * D * D + k * D + j];
                Wpt[l * D * D + j * D + k] = (bf16_t)(a * w);
                acc = fmaf(c, w, acc);
            }
            bp[l * D + j] = acc;
        }
        return;
    }
    extern __shared__ int hist[];
    const int r = blockIdx.x, p = blockIdx.y, dirz = blockIdx.z;
    for (int i = tid; i < RSZC; i += 256) hist[i] = 0;
    __syncthreads();
    const int base = r * RSZC;
    const int4* ids = (const int4*)(ei + dirz * NE + p * CSZ);
    for (int i = tid; i < CSZ / 4; i += 256) {
        int4 v = ids[i];
        int d0 = v.x - base, d1 = v.y - base, d2 = v.z - base, d3 = v.w - base;
        if ((unsigned)d0 < RSZC) atomicAdd(&hist[d0], 1);
        if ((unsigned)d1 < RSZC) atomicAdd(&hist[d1], 1);
        if ((unsigned)d2 < RSZC) atomicAdd(&hist[d2], 1);
        if ((unsigned)d3 < RSZC) atomicAdd(&hist[d3], 1);
    }
    __syncthreads();
    int* dst = (dirz == 0 ? PR : PC) + p * NNP + base;
    for (int i = tid; i < RSZC; i += 256) dst[i] = hist[i];
}

// fused: rowsum->dis, colscan->cnt + per-chunk offsets in PC, block-local scan
__global__ void csr_mid(const int* __restrict__ PR, int* __restrict__ PC,
                        float* __restrict__ dis, int* __restrict__ cnt,
                        int* __restrict__ colp, int* __restrict__ bsum) {
    __shared__ int s[256];
    int t = threadIdx.x;
    int i = blockIdx.x * 256 + t;
    int run = 0;
    if (i < NN) {
        int dg = 0;
#pragma unroll 8
        for (int k = 0; k < NCHUNK; ++k) dg += PR[k * NNP + i];
        dis[i] = rsqrtf((float)(dg + 1));
        for (int k = 0; k < NCHUNK; ++k) {
            int v = PC[k * NNP + i];
            PC[k * NNP + i] = run;
            run += v;
        }
        cnt[i] = run;
    }
    s[t] = run;
    __syncthreads();
    for (int o = 1; o < 256; o <<= 1) {
        int add = (t >= o) ? s[t - o] : 0;
        __syncthreads();
        s[t] += add;
        __syncthreads();
    }
    if (i < NN) colp[i] = s[t] - run;  // local exclusive
    if (t == 255) bsum[blockIdx.x] = s[255];
}

// scan3 with inlined block-offset reduction
__global__ void scan3(int* __restrict__ colp, const int* __restrict__ bsum,
                      const int* __restrict__ cnt, int* __restrict__ ends) {
    __shared__ int s[256];
    int t = threadIdx.x;
    int bid = blockIdx.x;
    s[t] = (t < bid) ? bsum[t] : 0;   // NB=196 <= 256
    __syncthreads();
    for (int o = 128; o; o >>= 1) {
        if (t < o) s[t] += s[t + o];
        __syncthreads();
    }
    int boff = s[0];
    int i = bid * 256 + t;
    if (i < NN) {
        int v = colp[i] + boff;
        colp[i] = v;
        ends[i] = v + cnt[i];
    }
}

// atomic-free(global) CSR fill; packed entries: src idx (lo16) | bf16 dis[src] (hi16)
__global__ __launch_bounds__(256) void fill_part(const int* __restrict__ ei,
                                                 const int* __restrict__ colp,
                                                 const int* __restrict__ CPS,
                                                 const float* __restrict__ dis,
                                                 unsigned int* __restrict__ srcs) {
    __shared__ int curs[RSZF];
    const int r = blockIdx.x, p = blockIdx.y;
    const int tid = threadIdx.x;
    const int base = r * RSZF;
    for (int i = tid; i < RSZF; i += 256)
        curs[i] = colp[base + i] + CPS[p * NNP + base + i];
    __syncthreads();
    const int4* rows = (const int4*)(ei + p * CSZ);
    const int4* cols = (const int4*)(ei + NE + p * CSZ);
    for (int i = tid; i < CSZ / 4; i += 256) {
        int4 rv = rows[i];
        int4 cv = cols[i];
        int d;
        d = cv.x - base;
        if ((unsigned)d < RSZF)
            srcs[atomicAdd(&curs[d], 1)] =
                (unsigned int)rv.x | ((unsigned int)f2bf_bits(dis[rv.x]) << 16);
        d = cv.y - base;
        if ((unsigned)d < RSZF)
            srcs[atomicAdd(&curs[d], 1)] =
                (unsigned int)rv.y | ((unsigned int)f2bf_bits(dis[rv.y]) << 16);
        d = cv.z - base;
        if ((unsigned)d < RSZF)
            srcs[atomicAdd(&curs[d], 1)] =
                (unsigned int)rv.z | ((unsigned int)f2bf_bits(dis[rv.z]) << 16);
        d = cv.w - base;
        if ((unsigned)d < RSZF)
            srcs[atomicAdd(&curs[d], 1)] =
                (unsigned int)rv.w | ((unsigned int)f2bf_bits(dis[rv.w]) << 16);
    }
}

// FUSED layers 0+1 (dense, no serial gather): per block, 64 rows:
// h0 = relu(x @ Wpt0 + bp0) -> swizzled LDS -> out = h0 @ Wpt1 + bp1
__global__ __launch_bounds__(256) void gemm01(const float* __restrict__ X,
                                              const bf16_t* __restrict__ Bt0,
                                              const bf16_t* __restrict__ Bt1,
                                              const float* __restrict__ bias0,
                                              const float* __restrict__ bias1,
                                              bf16_t* __restrict__ out) {
    __shared__ __align__(16) unsigned short As[64 * 128];
    const int tid = threadIdx.x;
    const int wv = tid >> 6;
    const int lane = tid & 63;
    const int l15 = lane & 15;
    const int l4 = lane >> 4;
    const int row0 = blockIdx.x * 64;

    // phase A: GEMM0 from global fp32 x
    bf16x8 afrag[4];
    {
        int r = row0 + wv * 16 + l15;
        int rc = (r < NN) ? r : (NN - 1);
#pragma unroll
        for (int kk = 0; kk < 4; ++kk) {
            int off = rc * D + kk * 32 + l4 * 8;
            float4 f0 = *(const float4*)(X + off);
            float4 f1 = *(const float4*)(X + off + 4);
            bf16x8 a;
            a[0] = (bf16_t)f0.x; a[1] = (bf16_t)f0.y;
            a[2] = (bf16_t)f0.z; a[3] = (bf16_t)f0.w;
            a[4] = (bf16_t)f1.x; a[5] = (bf16_t)f1.y;
            a[6] = (bf16_t)f1.z; a[7] = (bf16_t)f1.w;
            afrag[kk] = a;
        }
    }
    f32x4 acc[8];
#pragma unroll
    for (int n = 0; n < 8; ++n) acc[n] = (f32x4){0.f, 0.f, 0.f, 0.f};
#pragma unroll
    for (int n = 0; n < 8; ++n) {
#pragma unroll
        for (int kk = 0; kk < 4; ++kk) {
            bf16x8 bfrag = *(const bf16x8*)(Bt0 + (n * 16 + l15) * D + kk * 32 + l4 * 8);
            acc[n] = __builtin_amdgcn_mfma_f32_16x16x32_bf16(afrag[kk], bfrag, acc[n], 0, 0, 0);
        }
    }
    // epilogue -> swizzled LDS (16B unit u of row rl stored at u ^ (rl&7))
#pragma unroll
    for (int n = 0; n < 8; ++n) {
        int col = n * 16 + l15;
        float bv = bias0[col];
#pragma unroll
        for (int r = 0; r < 4; ++r) {
            int rl = wv * 16 + l4 * 4 + r;
            float v = fmaxf(acc[n][r] + bv, 0.f);
            int cs = ((col >> 3) ^ (rl & 7));
            As[rl * 128 + cs * 8 + (col & 7)] = f2bf_bits(v);
        }
    }
    __syncthreads();

    // phase B: GEMM1 from LDS
    const int rl = wv * 16 + l15;
    bf16x8 af2[4];
#pragma unroll
    for (int kk = 0; kk < 4; ++kk) {
        int cs = (kk * 4 + l4) ^ (rl & 7);
        af2[kk] = *(const bf16x8*)&As[rl * 128 + cs * 8];
    }
#pragma unroll
    for (int n = 0; n < 8; ++n) acc[n] = (f32x4){0.f, 0.f, 0.f, 0.f};
#pragma unroll
    for (int n = 0; n < 8; ++n) {
#pragma unroll
        for (int kk = 0; kk < 4; ++kk) {
            bf16x8 bfrag = *(const bf16x8*)(Bt1 + (n * 16 + l15) * D + kk * 32 + l4 * 8);
            acc[n] = __builtin_amdgcn_mfma_f32_16x16x32_bf16(af2[kk], bfrag, acc[n], 0, 0, 0);
        }
    }
#pragma unroll
    for (int n = 0; n < 8; ++n) {
        int col = n * 16 + l15;
        float bv = bias1[col];
#pragma unroll
        for (int r = 0; r < 4; ++r) {
            int row = row0 + wv * 16 + l4 * 4 + r;
            if (row < NN) out[(size_t)row * D + col] = (bf16_t)(acc[n][r] + bv);
        }
    }
}

// MFMA bf16 GEMM (layer 2): out = A @ Bt + bias, A bf16
__global__ __launch_bounds__(256) void gemm_mfma(const bf16_t* __restrict__ A,
                                                 const bf16_t* __restrict__ Bt,
                                                 const float* __restrict__ bias,
                                                 bf16_t* __restrict__ out) {
    const int tid = threadIdx.x;
    const int wv = tid >> 6;
    const int lane = tid & 63;
    const int l15 = lane & 15;
    const int l4 = lane >> 4;
    const int row0 = blockIdx.x * 64 + wv * 16;

    bf16x8 afrag[4];
    {
        int r = row0 + l15;
        int rc = (r < NN) ? r : (NN - 1);
#pragma unroll
        for (int kk = 0; kk < 4; ++kk)
            afrag[kk] = *(const bf16x8*)(A + rc * D + kk * 32 + l4 * 8);
    }
    f32x4 acc[8];
#pragma unroll
    for (int n = 0; n < 8; ++n) acc[n] = (f32x4){0.f, 0.f, 0.f, 0.f};
#pragma unroll
    for (int n = 0; n < 8; ++n) {
#pragma unroll
        for (int kk = 0; kk < 4; ++kk) {
            bf16x8 bfrag = *(const bf16x8*)(Bt + (n * 16 + l15) * D + kk * 32 + l4 * 8);
            acc[n] = __builtin_amdgcn_mfma_f32_16x16x32_bf16(afrag[kk], bfrag, acc[n], 0, 0, 0);
        }
    }
#pragma unroll
    for (int n = 0; n < 8; ++n) {
        int col = n * 16 + l15;
        float bv = bias[col];
#pragma unroll
        for (int r = 0; r < 4; ++r) {
            int row = row0 + l4 * 4 + r;
            if (row < NN) out[(size_t)row * D + col] = (bf16_t)(acc[n][r] + bv);
        }
    }
}

// gather propagate (R7 proven shape): one wave per node, unroll x4, packed srcs.
// POST 0: out bf16 = relu(v + bias);  POST 1: out bf16 = v
template <int POST>
__global__ __launch_bounds__(256) void prop_gather(
    const int* __restrict__ colp, const int* __restrict__ ends,
    const unsigned int* __restrict__ srcs, const float* __restrict__ dis,
    const bf16_t* __restrict__ hin, bf16_t* __restrict__ hout,
    const float* __restrict__ bias) {
    int n = blockIdx.x * 4 + (threadIdx.x >> 6);
    n = __builtin_amdgcn_readfirstlane(n);   // wave-uniform: scalarize CSR chain
    int lane = threadIdx.x & 63;
    if (n >= NN) return;
    const int start = colp[n];
    const int end = ends[n];
    const float dn = dis[n];
    unsigned int u = ((const unsigned int*)(hin + (size_t)n * D))[lane];
    float ax = dn * bf_lo(u), ay = dn * bf_hi(u);
    int i = start;
    for (; i + 3 < end; i += 4) {
        unsigned int e0 = srcs[i], e1 = srcs[i + 1], e2 = srcs[i + 2], e3 = srcs[i + 3];
        unsigned int u0 = ((const unsigned int*)(hin + (size_t)(e0 & 0xFFFFu) * D))[lane];
        unsigned int u1 = ((const unsigned int*)(hin + (size_t)(e1 & 0xFFFFu) * D))[lane];
        unsigned int u2 = ((const unsigned int*)(hin + (size_t)(e2 & 0xFFFFu) * D))[lane];
        unsigned int u3 = ((const unsigned int*)(hin + (size_t)(e3 & 0xFFFFu) * D))[lane];
        float w0 = bf_hi(e0), w1 = bf_hi(e1), w2 = bf_hi(e2), w3 = bf_hi(e3);
        ax = fmaf(w0, bf_lo(u0), ax); ay = fmaf(w0, bf_hi(u0), ay);
        ax = fmaf(w1, bf_lo(u1), ax); ay = fmaf(w1, bf_hi(u1), ay);
        ax = fmaf(w2, bf_lo(u2), ax); ay = fmaf(w2, bf_hi(u2), ay);
        ax = fmaf(w3, bf_lo(u3), ax); ay = fmaf(w3, bf_hi(u3), ay);
    }
    for (; i < end; ++i) {
        unsigned int e0 = srcs[i];
        unsigned int u0 = ((const unsigned int*)(hin + (size_t)(e0 & 0xFFFFu) * D))[lane];
        float w0 = bf_hi(e0);
        ax = fmaf(w0, bf_lo(u0), ax); ay = fmaf(w0, bf_hi(u0), ay);
    }
    float vx = dn * ax, vy = dn * ay;
    if (POST == 0) {
        float2 bb = ((const float2*)bias)[lane];
        vx = fmaxf(vx + bb.x, 0.f);
        vy = fmaxf(vy + bb.y, 0.f);
    }
    unsigned int pk = (unsigned int)f2bf_bits(vx) | ((unsigned int)f2bf_bits(vy) << 16);
    ((unsigned int*)(hout + (size_t)n * D))[lane] = pk;
}

// node head on bf16 node_rep: 32-lane groups, 4 bf16/lane
__global__ __launch_bounds__(256) void node_kernel(
    const bf16_t* __restrict__ h, const float* __restrict__ bh1,
    const float* __restrict__ We, const float* __restrict__ Wn,
    const float* __restrict__ bnb, const int* __restrict__ batch,
    float* __restrict__ nkey_out, float* __restrict__ t1, float* __restrict__ t2,
    float* __restrict__ accN) {
    __shared__ float binK[NG], binE[NG], binZ[NG], binC[NG];
    const int tid = threadIdx.x;
    for (int i = tid; i < NG; i += 256) { binK[i] = 0.f; binE[i] = 0.f; binZ[i] = 0.f; binC[i] = 0.f; }
    __syncthreads();

    const int CHUNK = 98;
    int start = blockIdx.x * CHUNK;
    int end = min(start + CHUNK, NN);
    int sub = tid >> 5;
    int l32 = tid & 31;
    float bnb0 = bnb[0];

    float4 w1 = ((const float4*)We)[l32];
    float4 w2 = ((const float4*)(We + D))[l32];
    float4 wn = ((const float4*)Wn)[l32];
    float4 bb = ((const float4*)bh1)[l32];

    for (int n = start + sub; n < end; n += 8) {
        uint2 pk = ((const uint2*)(h + (size_t)n * D))[l32];
        float v0 = bf_lo(pk.x) + bb.x;
        float v1 = bf_hi(pk.x) + bb.y;
        float v2 = bf_lo(pk.y) + bb.z;
        float v3 = bf_hi(pk.y) + bb.w;
        float s1 = v0 * w1.x + v1 * w1.y + v2 * w1.z + v3 * w1.w;
        float s2 = v0 * w2.x + v1 * w2.y + v2 * w2.z + v3 * w2.w;
        float s3 = v0 * wn.x + v1 * wn.y + v2 * wn.z + v3 * wn.w;
        for (int o = 16; o; o >>= 1) {
            s1 += __shfl_xor(s1, o);
            s2 += __shfl_xor(s2, o);
            s3 += __shfl_xor(s3, o);
        }
        if (l32 == 0) {
            t1[n] = s1;
            t2[n] = s2;
            float nk = sigmoidf(s3 + bnb0);
            nkey_out[n] = nk;
            int g = batch[n];
            atomicAdd(&binK[g], nk);
            atomicAdd(&binE[g], 1.0f - nk);
            if (nk > 0.f) atomicAdd(&binZ[g], 1.0f);
            atomicAdd(&binC[g], 1.0f);
        }
    }
    __syncthreads();
    if (start < NN) {
        int glo = batch[start];
        int ghi = batch[end - 1];
        for (int g = glo + tid; g <= ghi; g += 256) {
            unsafeAtomicAdd(&accN[g], binK[g]);
            unsafeAtomicAdd(&accN[NG + g], binE[g]);
            unsafeAtomicAdd(&accN[2 * NG + g], binZ[g]);
            unsafeAtomicAdd(&accN[3 * NG + g], binC[g]);
        }
    }
}

// edge head + inlined final reduction (last block computes outputs)
__global__ __launch_bounds__(256) void edge_final(
    const int* __restrict__ ei, const float* __restrict__ t1,
    const float* __restrict__ t2, const float* __restrict__ be,
    const int* __restrict__ batch, float* __restrict__ ekey_out,
    float* __restrict__ accE, const float* __restrict__ accN,
    int* __restrict__ ctr, float* __restrict__ out) {
    __shared__ float binK[NG], binE[NG], binZ[NG], binC[NG];
    __shared__ int isLast;
    const int tid = threadIdx.x;
    for (int i = tid; i < NG; i += 256) { binK[i] = 0.f; binE[i] = 0.f; binZ[i] = 0.f; binC[i] = 0.f; }
    __syncthreads();
    float be0 = be[0];
    int stride4 = gridDim.x * 256;
    for (int q = blockIdx.x * 256 + tid; q < NE / 4; q += stride4) {
        int4 r4 = ((const int4*)ei)[q];
        int4 c4 = ((const int4*)(ei + NE))[q];
        float a0 = t1[r4.x], a1 = t1[r4.y], a2 = t1[r4.z], a3 = t1[r4.w];
        float b0 = t2[c4.x], b1 = t2[c4.y], b2 = t2[c4.z], b3 = t2[c4.w];
        int g0 = batch[r4.x], g1 = batch[r4.y], g2 = batch[r4.z], g3 = batch[r4.w];
        float e0 = sigmoidf(a0 + b0 + be0);
        float e1 = sigmoidf(a1 + b1 + be0);
        float e2 = sigmoidf(a2 + b2 + be0);
        float e3 = sigmoidf(a3 + b3 + be0);
        ((float4*)ekey_out)[q] = make_float4(e0, e1, e2, e3);
        atomicAdd(&binK[g0], e0); atomicAdd(&binE[g0], 1.0f - e0);
        if (e0 > 0.f) atomicAdd(&binZ[g0], 1.0f);
        atomicAdd(&binC[g0], 1.0f);
        atomicAdd(&binK[g1], e1); atomicAdd(&binE[g1], 1.0f - e1);
        if (e1 > 0.f) atomicAdd(&binZ[g1], 1.0f);
        atomicAdd(&binC[g1], 1.0f);
        atomicAdd(&binK[g2], e2); atomicAdd(&binE[g2], 1.0f - e2);
        if (e2 > 0.f) atomicAdd(&binZ[g2], 1.0f);
        atomicAdd(&binC[g2], 1.0f);
        atomicAdd(&binK[g3], e3); atomicAdd(&binE[g3], 1.0f - e3);
        if (e3 > 0.f) atomicAdd(&binZ[g3], 1.0f);
        atomicAdd(&binC[g3], 1.0f);
    }
    __syncthreads();
    for (int g = tid; g < NG; g += 256) {
        if (binC[g] != 0.f) {
            unsafeAtomicAdd(&accE[g], binK[g]);
            unsafeAtomicAdd(&accE[NG + g], binE[g]);
            unsafeAtomicAdd(&accE[2 * NG + g], binZ[g]);
            unsafeAtomicAdd(&accE[3 * NG + g], binC[g]);
        }
    }
    __syncthreads();
    if (tid == 0) {
        __threadfence();
        int old = atomicAdd(ctr, 1);
        isLast = (old == (int)gridDim.x - 1);
    }
    __syncthreads();
    if (isLast) {
        __threadfence();
        for (int g = tid; g < NG; g += 256) {
            out[O_NKN + g] = accN[g] + 1e-8f;
            out[O_NEN + g] = accN[NG + g] + 1e-8f;
            out[O_EKN + g] = accE[g] + 1e-8f;
            out[O_EEN + g] = accE[NG + g] + 1e-8f;
            out[O_NZN + g] = accN[2 * NG + g] / accN[3 * NG + g];
            out[O_NZE + g] = accE[2 * NG + g] / accE[3 * NG + g];
        }
    }
}

extern "C" void kernel_launch(void* const* d_in, const int* in_sizes, int n_in,
                              void* d_out, int out_size, void* d_ws, size_t ws_size,
                              hipStream_t stream) {
    const float* x     = (const float*)d_in[0];
    const int*   ei    = (const int*)d_in[1];
    const int*   batch = (const int*)d_in[2];
    const float* W     = (const float*)d_in[4];
    const float* bh    = (const float*)d_in[5];   // [2][128]
    const float* gamma = (const float*)d_in[6];
    const float* beta  = (const float*)d_in[7];
    const float* mean  = (const float*)d_in[8];
    const float* var   = (const float*)d_in[9];
    const float* We    = (const float*)d_in[10];
    const float* be    = (const float*)d_in[11];
    const float* Wn    = (const float*)d_in[12];
    const float* bnb   = (const float*)d_in[13];

    float* ws  = (float*)d_ws;
    float* out = (float*)d_out;

    float*        accN = ws + OFF_ACCN;
    float*        accE = ws + OFF_ACCE;
    int*          ctr  = (int*)(ws + OFF_CTR);
    float*        dis  = ws + OFF_DIS;
    int*          cnt  = (int*)(ws + OFF_CNT);
    int*          colp = (int*)(ws + OFF_COLP);
    int*          ends = (int*)(ws + OFF_ENDS);
    int*          bsum = (int*)(ws + OFF_BSUM);
    float*        t1   = ws + OFF_T1;
    float*        t2   = ws + OFF_T2;
    float*        bp   = ws + OFF_BP;
    bf16_t*       Wpt  = (bf16_t*)(ws + OFF_WPT);
    int*          PR   = (int*)(ws + OFF_PR);
    int*          PC   = (int*)(ws + OFF_PC);
    unsigned int* srcs = (unsigned int*)(ws + OFF_SRCS);  // aliases PR
    bf16_t*       hbfA = (bf16_t*)(ws + OFF_HBFA);
    bf16_t*       hbfB = (bf16_t*)(ws + OFF_HBFB);

    hipMemsetAsync(d_ws, 0, (size_t)ZERO_FLOATS * sizeof(float), stream);

    // CSR count + prep_w (merged)
    count_prep<<<dim3(2, NCHUNK, 3), 256, RSZC * sizeof(int), stream>>>(
        ei, PR, PC, W, gamma, beta, mean, var, Wpt, bp);
    const int NB = (NN + 255) / 256;  // 196
    csr_mid<<<NB, 256, 0, stream>>>(PR, PC, dis, cnt, colp, bsum);
    scan3<<<NB, 256, 0, stream>>>(colp, bsum, cnt, ends);
    fill_part<<<dim3(4, NCHUNK), 256, 0, stream>>>(ei, colp, PC, dis, srcs);

    const int GB = (NN + 63) / 64;  // 782
    // layers 0+1 fused: hbfB = bf16( relu(x@Wp0+bp0) @ Wp1 + bp1 )
    gemm01<<<GB, 256, 0, stream>>>(x, Wpt, Wpt + D * D, bp, bp + D, hbfB);
    // propagate 1 + fused relu(v + bh0): hbfA = bf16(relu(P(hbfB) + bh0))
    prop_gather<0><<<12500, 256, 0, stream>>>(colp, ends, srcs, dis, hbfB, hbfA, bh);
    // layer 2 linear: hbfB = bf16(hbfA @ Wp2 + bp2)
    gemm_mfma<<<GB, 256, 0, stream>>>(hbfA, Wpt + 2 * D * D, bp + 2 * D, hbfB);
    // propagate 2: hbfA = bf16(P(hbfB))  (node_rep)
    prop_gather<1><<<12500, 256, 0, stream>>>(colp, ends, srcs, dis, hbfB, hbfA, nullptr);

    node_kernel<<<512, 256, 0, stream>>>(hbfA, bh + D, We, Wn, bnb, batch,
                                         out + O_NKEY, t1, t2, accN);
    edge_final<<<EDGE_BLOCKS, 256, 0, stream>>>(ei, t1, t2, be, batch,
                                                out + O_EKEY, accE, accN, ctr, out);
}

// Round 11
// 214.553 us; speedup vs baseline: 1.2215x; 1.1493x over previous
//
#include <hip/hip_runtime.h>
#include <cstddef>
#include <cstring>

#define NN 50000
#define NNP 50048
#define NE 800000
#define D 128
#define NG 512
#define BN_EPS 1e-5f
#define RSZC 25000    // count: nodes per range (2 ranges, 100 KB dyn LDS)
#define RSZF 12500    // fill: nodes per range (4 ranges, 50 KB LDS)
#define NCHUNK 64
#define CSZ 12500     // edges per chunk
#define EDGE_BLOCKS 256

typedef __bf16 bf16_t;
typedef __bf16 bf16x8 __attribute__((ext_vector_type(8)));
typedef float f32x4 __attribute__((ext_vector_type(4)));

// ---- workspace layout (float offsets) ----
#define OFF_ACCN 0            // float[4*512]
#define OFF_ACCE 2048         // float[4*512]
#define OFF_CTR  4096         // int[1] + pad
#define ZERO_FLOATS 4160      // zeroed region = [0, here)
#define OFF_DIS  4160         // float[50048]
#define OFF_CNT  54208        // int[50048]
#define OFF_COLP 104256      // int[50048]
#define OFF_ENDS 154304      // int[50048]
#define OFF_BSUM 204352      // int[256]
#define OFF_T1   204800      // float[50048]
#define OFF_T2   254848      // float[50048]
#define OFF_BP   304896      // float[3*128 padded]
#define OFF_WPT  305408      // bf16[3*128*128] (24576 floats)
#define OFF_PR   329984      // int[64][50048] = 3203072
#define OFF_PC   3533056     // int[64][50048] = 3203072 (CPS after csr_mid)
#define OFF_SRCS OFF_PR      // uint[800000], aliases PR (dead after csr_mid)
#define OFF_HBFA 7536128     // bf16[50048*128] (3203072 floats)
#define OFF_HBFB 10739200    // bf16[50048*128]

// ---- output layout (float offsets in d_out) ----
#define O_NKEY 0
#define O_EKEY 50000
#define O_NKN  850000
#define O_NEN  850512
#define O_EKN  851024
#define O_EEN  851536
#define O_NZN  852048
#define O_NZE  852560

__device__ __forceinline__ float sigmoidf(float x) {
    return 1.0f / (1.0f + expf(-x));
}

__device__ __forceinline__ unsigned short f2bf_bits(float f) {
    bf16_t h = (bf16_t)f;
    unsigned short u;
    __builtin_memcpy(&u, &h, 2);
    return u;
}

__device__ __forceinline__ float bf_lo(unsigned int u) {
    return __uint_as_float(u << 16);
}
__device__ __forceinline__ float bf_hi(unsigned int u) {
    return __uint_as_float(u & 0xFFFF0000u);
}

// count histograms (2 node ranges x 64 chunks x 2 dirs) + prep_w rides on z==2.
__global__ __launch_bounds__(256) void count_prep(const int* __restrict__ ei,
                                                  int* __restrict__ PR,
                                                  int* __restrict__ PC,
                                                  const float* __restrict__ W,
                                                  const float* __restrict__ gamma,
                                                  const float* __restrict__ beta,
                                                  const float* __restrict__ mean,
                                                  const float* __restrict__ var,
                                                  bf16_t* __restrict__ Wpt,
                                                  float* __restrict__ bp) {
    const int tid = threadIdx.x;
    if (blockIdx.z == 2) {
        if (blockIdx.x == 0 && blockIdx.y < 3 && tid < D) {
            int l = blockIdx.y;
            int j = tid;
            float acc = 0.f;
            for (int k = 0; k < D; ++k) {
                float a = gamma[l * D + k] * rsqrtf(var[l * D + k] + BN_EPS);
                float c = beta[l * D + k] - mean[l * D + k] * a;
                float w = W[l * D * D + k * D + j];
                Wpt[l * D * D + j * D + k] = (bf16_t)(a * w);
                acc = fmaf(c, w, acc);
            }
            bp[l * D + j] = acc;
        }
        return;
    }
    extern __shared__ int hist[];
    const int r = blockIdx.x, p = blockIdx.y, dirz = blockIdx.z;
    for (int i = tid; i < RSZC; i += 256) hist[i] = 0;
    __syncthreads();
    const int base = r * RSZC;
    const int4* ids = (const int4*)(ei + dirz * NE + p * CSZ);
    for (int i = tid; i < CSZ / 4; i += 256) {
        int4 v = ids[i];
        int d0 = v.x - base, d1 = v.y - base, d2 = v.z - base, d3 = v.w - base;
        if ((unsigned)d0 < RSZC) atomicAdd(&hist[d0], 1);
        if ((unsigned)d1 < RSZC) atomicAdd(&hist[d1], 1);
        if ((unsigned)d2 < RSZC) atomicAdd(&hist[d2], 1);
        if ((unsigned)d3 < RSZC) atomicAdd(&hist[d3], 1);
    }
    __syncthreads();
    int* dst = (dirz == 0 ? PR : PC) + p * NNP + base;
    for (int i = tid; i < RSZC; i += 256) dst[i] = hist[i];
}

// fused: rowsum->dis, colscan->cnt + per-chunk offsets in PC, block-local scan
__global__ void csr_mid(const int* __restrict__ PR, int* __restrict__ PC,
                        float* __restrict__ dis, int* __restrict__ cnt,
                        int* __restrict__ colp, int* __restrict__ bsum) {
    __shared__ int s[256];
    int t = threadIdx.x;
    int i = blockIdx.x * 256 + t;
    int run = 0;
    if (i < NN) {
        int dg = 0;
#pragma unroll 8
        for (int k = 0; k < NCHUNK; ++k) dg += PR[k * NNP + i];
        dis[i] = rsqrtf((float)(dg + 1));
        for (int k = 0; k < NCHUNK; ++k) {
            int v = PC[k * NNP + i];
            PC[k * NNP + i] = run;
            run += v;
        }
        cnt[i] = run;
    }
    s[t] = run;
    __syncthreads();
    for (int o = 1; o < 256; o <<= 1) {
        int add = (t >= o) ? s[t - o] : 0;
        __syncthreads();
        s[t] += add;
        __syncthreads();
    }
    if (i < NN) colp[i] = s[t] - run;  // local exclusive
    if (t == 255) bsum[blockIdx.x] = s[255];
}

// scan3 with inlined block-offset reduction
__global__ void scan3(int* __restrict__ colp, const int* __restrict__ bsum,
                      const int* __restrict__ cnt, int* __restrict__ ends) {
    __shared__ int s[256];
    int t = threadIdx.x;
    int bid = blockIdx.x;
    s[t] = (t < bid) ? bsum[t] : 0;   // NB=196 <= 256
    __syncthreads();
    for (int o = 128; o; o >>= 1) {
        if (t < o) s[t] += s[t + o];
        __syncthreads();
    }
    int boff = s[0];
    int i = bid * 256 + t;
    if (i < NN) {
        int v = colp[i] + boff;
        colp[i] = v;
        ends[i] = v + cnt[i];
    }
}

// atomic-free(global) CSR fill; packed entries: src idx (lo16) | bf16 dis[src] (hi16)
__global__ __launch_bounds__(256) void fill_part(const int* __restrict__ ei,
                                                 const int* __restrict__ colp,
                                                 const int* __restrict__ CPS,
                                                 const float* __restrict__ dis,
                                                 unsigned int* __restrict__ srcs) {
    __shared__ int curs[RSZF];
    const int r = blockIdx.x, p = blockIdx.y;
    const int tid = threadIdx.x;
    const int base = r * RSZF;
    for (int i = tid; i < RSZF; i += 256)
        curs[i] = colp[base + i] + CPS[p * NNP + base + i];
    __syncthreads();
    const int4* rows = (const int4*)(ei + p * CSZ);
    const int4* cols = (const int4*)(ei + NE + p * CSZ);
    for (int i = tid; i < CSZ / 4; i += 256) {
        int4 rv = rows[i];
        int4 cv = cols[i];
        int d;
        d = cv.x - base;
        if ((unsigned)d < RSZF)
            srcs[atomicAdd(&curs[d], 1)] =
                (unsigned int)rv.x | ((unsigned int)f2bf_bits(dis[rv.x]) << 16);
        d = cv.y - base;
        if ((unsigned)d < RSZF)
            srcs[atomicAdd(&curs[d], 1)] =
                (unsigned int)rv.y | ((unsigned int)f2bf_bits(dis[rv.y]) << 16);
        d = cv.z - base;
        if ((unsigned)d < RSZF)
            srcs[atomicAdd(&curs[d], 1)] =
                (unsigned int)rv.z | ((unsigned int)f2bf_bits(dis[rv.z]) << 16);
        d = cv.w - base;
        if ((unsigned)d < RSZF)
            srcs[atomicAdd(&curs[d], 1)] =
                (unsigned int)rv.w | ((unsigned int)f2bf_bits(dis[rv.w]) << 16);
    }
}

// FUSED layers 0+1 with B0,B1 staged in LDS (XOR-swizzled 16B units).
// h0 = relu(x @ B0 + bias0) -> swizzled LDS -> out = h0 @ B1 + bias1
__global__ __launch_bounds__(256) void gemm01(const float* __restrict__ X,
                                              const bf16_t* __restrict__ Bt0,
                                              const bf16_t* __restrict__ Bt1,
                                              const float* __restrict__ bias0,
                                              const float* __restrict__ bias1,
                                              bf16_t* __restrict__ out) {
    extern __shared__ __align__(16) unsigned short smem[];
    unsigned short* Bs0 = smem;             // 128*128 bf16 = 32 KB
    unsigned short* Bs1 = smem + 16384;     // 32 KB
    unsigned short* As  = smem + 32768;     // 64*128 bf16 = 16 KB
    const int tid = threadIdx.x;
    const int wv = tid >> 6;
    const int lane = tid & 63;
    const int l15 = lane & 15;
    const int l4 = lane >> 4;
    const int row0 = blockIdx.x * 64;

    // stage B0, B1 into LDS: unit u (16B) of row r stored at u ^ (r&7)
    for (int q = tid; q < 2048; q += 256) {
        int r = q >> 4, u = q & 15;
        int us = (u ^ (r & 7)) * 8;
        *(uint4*)&Bs0[r * 128 + us] = *(const uint4*)(Bt0 + r * D + u * 8);
        *(uint4*)&Bs1[r * 128 + us] = *(const uint4*)(Bt1 + r * D + u * 8);
    }

    // A fragments from global fp32 x (independent scatter loads)
    bf16x8 afrag[4];
    {
        int r = row0 + wv * 16 + l15;
        int rc = (r < NN) ? r : (NN - 1);
#pragma unroll
        for (int kk = 0; kk < 4; ++kk) {
            int off = rc * D + kk * 32 + l4 * 8;
            float4 f0 = *(const float4*)(X + off);
            float4 f1 = *(const float4*)(X + off + 4);
            bf16x8 a;
            a[0] = (bf16_t)f0.x; a[1] = (bf16_t)f0.y;
            a[2] = (bf16_t)f0.z; a[3] = (bf16_t)f0.w;
            a[4] = (bf16_t)f1.x; a[5] = (bf16_t)f1.y;
            a[6] = (bf16_t)f1.z; a[7] = (bf16_t)f1.w;
            afrag[kk] = a;
        }
    }
    __syncthreads();

    const int rsw = l15 & 7;   // B-row swizzle key (row = n*16+l15 -> &7 = l15&7)
    f32x4 acc[8];
#pragma unroll
    for (int n = 0; n < 8; ++n) acc[n] = (f32x4){0.f, 0.f, 0.f, 0.f};
#pragma unroll
    for (int n = 0; n < 8; ++n) {
#pragma unroll
        for (int kk = 0; kk < 4; ++kk) {
            bf16x8 bfrag = *(const bf16x8*)&Bs0[(n * 16 + l15) * 128 + ((kk * 4 + l4) ^ rsw) * 8];
            acc[n] = __builtin_amdgcn_mfma_f32_16x16x32_bf16(afrag[kk], bfrag, acc[n], 0, 0, 0);
        }
    }
    // epilogue -> swizzled As
#pragma unroll
    for (int n = 0; n < 8; ++n) {
        int col = n * 16 + l15;
        float bv = bias0[col];
#pragma unroll
        for (int r = 0; r < 4; ++r) {
            int rl = wv * 16 + l4 * 4 + r;
            float v = fmaxf(acc[n][r] + bv, 0.f);
            int cs = ((col >> 3) ^ (rl & 7));
            As[rl * 128 + cs * 8 + (col & 7)] = f2bf_bits(v);
        }
    }
    __syncthreads();

    // phase B: A from As (swizzled), B from Bs1
    const int rl = wv * 16 + l15;
    bf16x8 af2[4];
#pragma unroll
    for (int kk = 0; kk < 4; ++kk) {
        int cs = (kk * 4 + l4) ^ (rl & 7);
        af2[kk] = *(const bf16x8*)&As[rl * 128 + cs * 8];
    }
#pragma unroll
    for (int n = 0; n < 8; ++n) acc[n] = (f32x4){0.f, 0.f, 0.f, 0.f};
#pragma unroll
    for (int n = 0; n < 8; ++n) {
#pragma unroll
        for (int kk = 0; kk < 4; ++kk) {
            bf16x8 bfrag = *(const bf16x8*)&Bs1[(n * 16 + l15) * 128 + ((kk * 4 + l4) ^ rsw) * 8];
            acc[n] = __builtin_amdgcn_mfma_f32_16x16x32_bf16(af2[kk], bfrag, acc[n], 0, 0, 0);
        }
    }
#pragma unroll
    for (int n = 0; n < 8; ++n) {
        int col = n * 16 + l15;
        float bv = bias1[col];
#pragma unroll
        for (int r = 0; r < 4; ++r) {
            int row = row0 + wv * 16 + l4 * 4 + r;
            if (row < NN) out[(size_t)row * D + col] = (bf16_t)(acc[n][r] + bv);
        }
    }
}

// layer-2 GEMM with B staged in LDS: out = A @ Bt + bias, A bf16
__global__ __launch_bounds__(256) void gemm2(const bf16_t* __restrict__ A,
                                             const bf16_t* __restrict__ Bt,
                                             const float* __restrict__ bias,
                                             bf16_t* __restrict__ out) {
    __shared__ __align__(16) unsigned short Bs[128 * 128];  // 32 KB
    const int tid = threadIdx.x;
    const int wv = tid >> 6;
    const int lane = tid & 63;
    const int l15 = lane & 15;
    const int l4 = lane >> 4;
    const int row0 = blockIdx.x * 64 + wv * 16;

    for (int q = tid; q < 2048; q += 256) {
        int r = q >> 4, u = q & 15;
        *(uint4*)&Bs[r * 128 + (u ^ (r & 7)) * 8] = *(const uint4*)(Bt + r * D + u * 8);
    }

    bf16x8 afrag[4];
    {
        int r = row0 + l15;
        int rc = (r < NN) ? r : (NN - 1);
#pragma unroll
        for (int kk = 0; kk < 4; ++kk)
            afrag[kk] = *(const bf16x8*)(A + rc * D + kk * 32 + l4 * 8);
    }
    __syncthreads();

    const int rsw = l15 & 7;
    f32x4 acc[8];
#pragma unroll
    for (int n = 0; n < 8; ++n) acc[n] = (f32x4){0.f, 0.f, 0.f, 0.f};
#pragma unroll
    for (int n = 0; n < 8; ++n) {
#pragma unroll
        for (int kk = 0; kk < 4; ++kk) {
            bf16x8 bfrag = *(const bf16x8*)&Bs[(n * 16 + l15) * 128 + ((kk * 4 + l4) ^ rsw) * 8];
            acc[n] = __builtin_amdgcn_mfma_f32_16x16x32_bf16(afrag[kk], bfrag, acc[n], 0, 0, 0);
        }
    }
#pragma unroll
    for (int n = 0; n < 8; ++n) {
        int col = n * 16 + l15;
        float bv = bias[col];
#pragma unroll
        for (int r = 0; r < 4; ++r) {
            int row = row0 + l4 * 4 + r;
            if (row < NN) out[(size_t)row * D + col] = (bf16_t)(acc[n][r] + bv);
        }
    }
}

// gather propagate: one wave per node, unroll x4, packed srcs.
// POST 0: out bf16 = relu(v + bias);  POST 1: out bf16 = v
template <int POST>
__global__ __launch_bounds__(256) void prop_gather(
    const int* __restrict__ colp, const int* __restrict__ ends,
    const unsigned int* __restrict__ srcs, const float* __restrict__ dis,
    const bf16_t* __restrict__ hin, bf16_t* __restrict__ hout,
    const float* __restrict__ bias) {
    int n = blockIdx.x * 4 + (threadIdx.x >> 6);
    n = __builtin_amdgcn_readfirstlane(n);   // wave-uniform: scalarize CSR chain
    int lane = threadIdx.x & 63;
    if (n >= NN) return;
    const int start = colp[n];
    const int end = ends[n];
    const float dn = dis[n];
    unsigned int u = ((const unsigned int*)(hin + (size_t)n * D))[lane];
    float ax = dn * bf_lo(u), ay = dn * bf_hi(u);
    int i = start;
    for (; i + 3 < end; i += 4) {
        unsigned int e0 = srcs[i], e1 = srcs[i + 1], e2 = srcs[i + 2], e3 = srcs[i + 3];
        unsigned int u0 = ((const unsigned int*)(hin + (size_t)(e0 & 0xFFFFu) * D))[lane];
        unsigned int u1 = ((const unsigned int*)(hin + (size_t)(e1 & 0xFFFFu) * D))[lane];
        unsigned int u2 = ((const unsigned int*)(hin + (size_t)(e2 & 0xFFFFu) * D))[lane];
        unsigned int u3 = ((const unsigned int*)(hin + (size_t)(e3 & 0xFFFFu) * D))[lane];
        float w0 = bf_hi(e0), w1 = bf_hi(e1), w2 = bf_hi(e2), w3 = bf_hi(e3);
        ax = fmaf(w0, bf_lo(u0), ax); ay = fmaf(w0, bf_hi(u0), ay);
        ax = fmaf(w1, bf_lo(u1), ax); ay = fmaf(w1, bf_hi(u1), ay);
        ax = fmaf(w2, bf_lo(u2), ax); ay = fmaf(w2, bf_hi(u2), ay);
        ax = fmaf(w3, bf_lo(u3), ax); ay = fmaf(w3, bf_hi(u3), ay);
    }
    for (; i < end; ++i) {
        unsigned int e0 = srcs[i];
        unsigned int u0 = ((const unsigned int*)(hin + (size_t)(e0 & 0xFFFFu) * D))[lane];
        float w0 = bf_hi(e0);
        ax = fmaf(w0, bf_lo(u0), ax); ay = fmaf(w0, bf_hi(u0), ay);
    }
    float vx = dn * ax, vy = dn * ay;
    if (POST == 0) {
        float2 bb = ((const float2*)bias)[lane];
        vx = fmaxf(vx + bb.x, 0.f);
        vy = fmaxf(vy + bb.y, 0.f);
    }
    unsigned int pk = (unsigned int)f2bf_bits(vx) | ((unsigned int)f2bf_bits(vy) << 16);
    ((unsigned int*)(hout + (size_t)n * D))[lane] = pk;
}

// node head on bf16 node_rep: 32-lane groups, 4 bf16/lane
__global__ __launch_bounds__(256) void node_kernel(
    const bf16_t* __restrict__ h, const float* __restrict__ bh1,
    const float* __restrict__ We, const float* __restrict__ Wn,
    const float* __restrict__ bnb, const int* __restrict__ batch,
    float* __restrict__ nkey_out, float* __restrict__ t1, float* __restrict__ t2,
    float* __restrict__ accN) {
    __shared__ float binK[NG], binE[NG], binZ[NG], binC[NG];
    const int tid = threadIdx.x;
    for (int i = tid; i < NG; i += 256) { binK[i] = 0.f; binE[i] = 0.f; binZ[i] = 0.f; binC[i] = 0.f; }
    __syncthreads();

    const int CHUNK = 98;
    int start = blockIdx.x * CHUNK;
    int end = min(start + CHUNK, NN);
    int sub = tid >> 5;
    int l32 = tid & 31;
    float bnb0 = bnb[0];

    float4 w1 = ((const float4*)We)[l32];
    float4 w2 = ((const float4*)(We + D))[l32];
    float4 wn = ((const float4*)Wn)[l32];
    float4 bb = ((const float4*)bh1)[l32];

    for (int n = start + sub; n < end; n += 8) {
        uint2 pk = ((const uint2*)(h + (size_t)n * D))[l32];
        float v0 = bf_lo(pk.x) + bb.x;
        float v1 = bf_hi(pk.x) + bb.y;
        float v2 = bf_lo(pk.y) + bb.z;
        float v3 = bf_hi(pk.y) + bb.w;
        float s1 = v0 * w1.x + v1 * w1.y + v2 * w1.z + v3 * w1.w;
        float s2 = v0 * w2.x + v1 * w2.y + v2 * w2.z + v3 * w2.w;
        float s3 = v0 * wn.x + v1 * wn.y + v2 * wn.z + v3 * wn.w;
        for (int o = 16; o; o >>= 1) {
            s1 += __shfl_xor(s1, o);
            s2 += __shfl_xor(s2, o);
            s3 += __shfl_xor(s3, o);
        }
        if (l32 == 0) {
            t1[n] = s1;
            t2[n] = s2;
            float nk = sigmoidf(s3 + bnb0);
            nkey_out[n] = nk;
            int g = batch[n];
            atomicAdd(&binK[g], nk);
            atomicAdd(&binE[g], 1.0f - nk);
            if (nk > 0.f) atomicAdd(&binZ[g], 1.0f);
            atomicAdd(&binC[g], 1.0f);
        }
    }
    __syncthreads();
    if (start < NN) {
        int glo = batch[start];
        int ghi = batch[end - 1];
        for (int g = glo + tid; g <= ghi; g += 256) {
            unsafeAtomicAdd(&accN[g], binK[g]);
            unsafeAtomicAdd(&accN[NG + g], binE[g]);
            unsafeAtomicAdd(&accN[2 * NG + g], binZ[g]);
            unsafeAtomicAdd(&accN[3 * NG + g], binC[g]);
        }
    }
}

// edge head + inlined final reduction (last block computes outputs)
__global__ __launch_bounds__(256) void edge_final(
    const int* __restrict__ ei, const float* __restrict__ t1,
    const float* __restrict__ t2, const float* __restrict__ be,
    const int* __restrict__ batch, float* __restrict__ ekey_out,
    float* __restrict__ accE, const float* __restrict__ accN,
    int* __restrict__ ctr, float* __restrict__ out) {
    __shared__ float binK[NG], binE[NG], binZ[NG], binC[NG];
    __shared__ int isLast;
    const int tid = threadIdx.x;
    for (int i = tid; i < NG; i += 256) { binK[i] = 0.f; binE[i] = 0.f; binZ[i] = 0.f; binC[i] = 0.f; }
    __syncthreads();
    float be0 = be[0];
    int stride4 = gridDim.x * 256;
    for (int q = blockIdx.x * 256 + tid; q < NE / 4; q += stride4) {
        int4 r4 = ((const int4*)ei)[q];
        int4 c4 = ((const int4*)(ei + NE))[q];
        float a0 = t1[r4.x], a1 = t1[r4.y], a2 = t1[r4.z], a3 = t1[r4.w];
        float b0 = t2[c4.x], b1 = t2[c4.y], b2 = t2[c4.z], b3 = t2[c4.w];
        int g0 = batch[r4.x], g1 = batch[r4.y], g2 = batch[r4.z], g3 = batch[r4.w];
        float e0 = sigmoidf(a0 + b0 + be0);
        float e1 = sigmoidf(a1 + b1 + be0);
        float e2 = sigmoidf(a2 + b2 + be0);
        float e3 = sigmoidf(a3 + b3 + be0);
        ((float4*)ekey_out)[q] = make_float4(e0, e1, e2, e3);
        atomicAdd(&binK[g0], e0); atomicAdd(&binE[g0], 1.0f - e0);
        if (e0 > 0.f) atomicAdd(&binZ[g0], 1.0f);
        atomicAdd(&binC[g0], 1.0f);
        atomicAdd(&binK[g1], e1); atomicAdd(&binE[g1], 1.0f - e1);
        if (e1 > 0.f) atomicAdd(&binZ[g1], 1.0f);
        atomicAdd(&binC[g1], 1.0f);
        atomicAdd(&binK[g2], e2); atomicAdd(&binE[g2], 1.0f - e2);
        if (e2 > 0.f) atomicAdd(&binZ[g2], 1.0f);
        atomicAdd(&binC[g2], 1.0f);
        atomicAdd(&binK[g3], e3); atomicAdd(&binE[g3], 1.0f - e3);
        if (e3 > 0.f) atomicAdd(&binZ[g3], 1.0f);
        atomicAdd(&binC[g3], 1.0f);
    }
    __syncthreads();
    for (int g = tid; g < NG; g += 256) {
        if (binC[g] != 0.f) {
            unsafeAtomicAdd(&accE[g], binK[g]);
            unsafeAtomicAdd(&accE[NG + g], binE[g]);
            unsafeAtomicAdd(&accE[2 * NG + g], binZ[g]);
            unsafeAtomicAdd(&accE[3 * NG + g], binC[g]);
        }
    }
    __syncthreads();
    if (tid == 0) {
        __threadfence();
        int old = atomicAdd(ctr, 1);
        isLast = (old == (int)gridDim.x - 1);
    }
    __syncthreads();
    if (isLast) {
        __threadfence();
        for (int g = tid; g < NG; g += 256) {
            out[O_NKN + g] = accN[g] + 1e-8f;
            out[O_NEN + g] = accN[NG + g] + 1e-8f;
            out[O_EKN + g] = accE[g] + 1e-8f;
            out[O_EEN + g] = accE[NG + g] + 1e-8f;
            out[O_NZN + g] = accN[2 * NG + g] / accN[3 * NG + g];
            out[O_NZE + g] = accE[2 * NG + g] / accE[3 * NG + g];
        }
    }
}

extern "C" void kernel_launch(void* const* d_in, const int* in_sizes, int n_in,
                              void* d_out, int out_size, void* d_ws, size_t ws_size,
                              hipStream_t stream) {
    const float* x     = (const float*)d_in[0];
    const int*   ei    = (const int*)d_in[1];
    const int*   batch = (const int*)d_in[2];
    const float* W     = (const float*)d_in[4];
    const float* bh    = (const float*)d_in[5];   // [2][128]
    const float* gamma = (const float*)d_in[6];
    const float* beta  = (const float*)d_in[7];
    const float* mean  = (const float*)d_in[8];
    const float* var   = (const float*)d_in[9];
    const float* We    = (const float*)d_in[10];
    const float* be    = (const float*)d_in[11];
    const float* Wn    = (const float*)d_in[12];
    const float* bnb   = (const float*)d_in[13];

    float* ws  = (float*)d_ws;
    float* out = (float*)d_out;

    float*        accN = ws + OFF_ACCN;
    float*        accE = ws + OFF_ACCE;
    int*          ctr  = (int*)(ws + OFF_CTR);
    float*        dis  = ws + OFF_DIS;
    int*          cnt  = (int*)(ws + OFF_CNT);
    int*          colp = (int*)(ws + OFF_COLP);
    int*          ends = (int*)(ws + OFF_ENDS);
    int*          bsum = (int*)(ws + OFF_BSUM);
    float*        t1   = ws + OFF_T1;
    float*        t2   = ws + OFF_T2;
    float*        bp   = ws + OFF_BP;
    bf16_t*       Wpt  = (bf16_t*)(ws + OFF_WPT);
    int*          PR   = (int*)(ws + OFF_PR);
    int*          PC   = (int*)(ws + OFF_PC);
    unsigned int* srcs = (unsigned int*)(ws + OFF_SRCS);  // aliases PR
    bf16_t*       hbfA = (bf16_t*)(ws + OFF_HBFA);
    bf16_t*       hbfB = (bf16_t*)(ws + OFF_HBFB);

    hipMemsetAsync(d_ws, 0, (size_t)ZERO_FLOATS * sizeof(float), stream);

    // CSR count + prep_w (merged)
    count_prep<<<dim3(2, NCHUNK, 3), 256, RSZC * sizeof(int), stream>>>(
        ei, PR, PC, W, gamma, beta, mean, var, Wpt, bp);
    const int NB = (NN + 255) / 256;  // 196
    csr_mid<<<NB, 256, 0, stream>>>(PR, PC, dis, cnt, colp, bsum);
    scan3<<<NB, 256, 0, stream>>>(colp, bsum, cnt, ends);
    fill_part<<<dim3(4, NCHUNK), 256, 0, stream>>>(ei, colp, PC, dis, srcs);

    const int GB = (NN + 63) / 64;  // 782
    // layers 0+1 fused (B0,B1,h0 all in LDS): hbfB = bf16( relu(x@Wp0+bp0) @ Wp1 + bp1 )
    gemm01<<<GB, 256, 81920, stream>>>(x, Wpt, Wpt + D * D, bp, bp + D, hbfB);
    // propagate 1 + fused relu(v + bh0): hbfA = bf16(relu(P(hbfB) + bh0))
    prop_gather<0><<<12500, 256, 0, stream>>>(colp, ends, srcs, dis, hbfB, hbfA, bh);
    // layer 2 linear (B in LDS): hbfB = bf16(hbfA @ Wp2 + bp2)
    gemm2<<<GB, 256, 0, stream>>>(hbfA, Wpt + 2 * D * D, bp + 2 * D, hbfB);
    // propagate 2: hbfA = bf16(P(hbfB))  (node_rep)
    prop_gather<1><<<12500, 256, 0, stream>>>(colp, ends, srcs, dis, hbfB, hbfA, nullptr);

    node_kernel<<<512, 256, 0, stream>>>(hbfA, bh + D, We, Wn, bnb, batch,
                                         out + O_NKEY, t1, t2, accN);
    edge_final<<<EDGE_BLOCKS, 256, 0, stream>>>(ei, t1, t2, be, batch,
                                                out + O_EKEY, accE, accN, ctr, out);
}